// Round 2
// baseline (85.326 us; speedup 1.0000x reference)
//
#include <hip/hip_runtime.h>
#include <hip/hip_fp16.h>

// DRN layer — economized-cubic / moment factorization, TWO-KERNEL split (R6).
//
//  x = w*d2, |x| <= h = 0.1*(63/64)^2 = 0.0969.
//  exp(-x) ~= a0 - x + a2*x^2 - x^3/6   (Chebyshev-economized Taylor-4:
//      x^4 ~= h^2 x^2 - h^4/8 on [-h,h]; a2 = 1/2 + h^2/24, a0 = 1 - h^4/192)
//  Pw = a0*m0 * [1 + (-w)(N1 + (-w)(N2 + (-w)N3))],
//     N1 = M1/m0, N2 = a2*M2/m0, N3 = (1/6)*M3/m0,  M_n = sum_m d2^n P[i,k,m].
//  a0*m0 is (j,l)-independent -> cancels in softmax (a0 dropped entirely).
//  M_n from raw moments mom_0..mom_6 via binomial in z = -s_l.
//  poly in [0.905,1.10] -> product over 64 k within 2^+-9.3: ONE log2 per j,
//  exp2-softmax safe with NO max-shift.
//
// R6: structural experiment. R4 (34 us kernel after fill-subtract) is ~6x the
// VALU-issue floor; R5 (2x occupancy, same structure) regressed -> the stall
// is NOT plain issue starvation; suspects are the barrier-serialized phases +
// grid-capped 2 blocks/CU + per-jh duplicated n-plane work. This round:
//   K1 (grid 256): moments + n-plane per i, computed ONCE, no barriers, no LDS,
//      written coalesced to d_ws (float2: n1 fp32 | n2,n3 fp16x2; 8 MB total).
//   K2 (grid 2048 x 256thr): product loop + softmax. NO LDS, NO barriers ->
//      occupancy is VGPR-limited only (~50 live -> 8 waves/SIMD). bid layout
//      jq*256+i puts all 8 j-blocks of an i on XCD i%8 = the XCD whose L2
//      holds K1's n-plane write (perf heuristic only, not correctness).
// Math is bit-identical to R4 -> absmax must stay 1.2207e-4.

#define NUP 64
#define NLOW 64
#define QUP 64
#define QLOW 64

// ---------------------------------------------------------------------------
// K1: per-i n-plane (A,B,C moments combine), wave-local, barrier-free.
// block = 512 (8 waves); wave wv owns k in [8wv, 8wv+8).
// ---------------------------------------------------------------------------
__global__ __launch_bounds__(512, 2)
void drn_prep(const float* __restrict__ P, float2* __restrict__ nplane)
{
    const int i    = blockIdx.x;
    const int tid  = threadIdx.x;
    const int lane = tid & 63;
    const int wv   = __builtin_amdgcn_readfirstlane(tid >> 6);   // 0..7, uniform

    // ---- phase 1: raw moments mom_0..6 for this wave's 8 k ----
    // lane = (kk, mc): k = wv*8+kk ; m in [mc*8, mc*8+8)
    float t0 = 0.f, t1 = 0.f, t2 = 0.f, t3 = 0.f, t4 = 0.f, t5 = 0.f, t6 = 0.f;
    {
        const int kk = lane >> 3;
        const int mc = lane & 7;
        const int k  = wv * 8 + kk;
        const float* Pr = P + ((size_t)i * NLOW + k) * QLOW + mc * 8;
        const float4 pa = *reinterpret_cast<const float4*>(Pr);
        const float4 pb = *reinterpret_cast<const float4*>(Pr + 4);

        const float s0 = (float)(mc * 8) * 0.015625f;
#define ACCM(PV, S) { float f = (PV); const float s_ = (S); \
        t0 += f; f *= s_; t1 += f; f *= s_; t2 += f; f *= s_; t3 += f; \
        f *= s_; t4 += f; f *= s_; t5 += f; f *= s_; t6 += f; }
        ACCM(pa.x, s0);
        ACCM(pa.y, s0 + 0.015625f);
        ACCM(pa.z, s0 + 0.03125f);
        ACCM(pa.w, s0 + 0.046875f);
        ACCM(pb.x, s0 + 0.0625f);
        ACCM(pb.y, s0 + 0.078125f);
        ACCM(pb.z, s0 + 0.09375f);
        ACCM(pb.w, s0 + 0.109375f);
#undef ACCM
#define RED7(OFF) { t0 += __shfl_xor(t0, OFF, 64); t1 += __shfl_xor(t1, OFF, 64); \
        t2 += __shfl_xor(t2, OFF, 64); t3 += __shfl_xor(t3, OFF, 64); \
        t4 += __shfl_xor(t4, OFF, 64); t5 += __shfl_xor(t5, OFF, 64); \
        t6 += __shfl_xor(t6, OFF, 64); }
        RED7(1) RED7(2) RED7(4)
#undef RED7
        // every lane of 8-lane group kk now holds the full moments of k=wv*8+kk
    }

    // ---- phase 2 (fused, no barrier): 8-byte n(k,l) entries -> global ----
    const float s1l = (float)lane * 0.015625f;
    {
        const float A2 = 0.50039123f;            // 1/2 + h^2/24, h = 0.1*(63/64)^2
        const float C6 = 1.0f / 6.0f;
        const float z  = -s1l;
        const float z2 = z * z, z3 = z2 * z, z4 = z2 * z2, z5 = z4 * z, z6 = z4 * z2;
        const float b10 = z2,        b11 = 2.f * z;
        const float b20 = z4,        b21 = 4.f * z3, b22 = 6.f * z2, b23 = 4.f * z;
        const float b30 = z6,        b31 = 6.f * z5, b32 = 15.f * z4,
                    b33 = 20.f * z3, b34 = 15.f * z2, b35 = 6.f * z;

#pragma unroll
        for (int kk = 0; kk < 8; ++kk) {
            const int k = wv * 8 + kk;
            // wave-local broadcast (compile-time src lane -> v_readlane)
            const float m0 = __shfl(t0, kk * 8, 64);
            const float m1 = __shfl(t1, kk * 8, 64);
            const float m2 = __shfl(t2, kk * 8, 64);
            const float m3 = __shfl(t3, kk * 8, 64);
            const float m4 = __shfl(t4, kk * 8, 64);
            const float m5 = __shfl(t5, kk * 8, 64);
            const float m6 = __shfl(t6, kk * 8, 64);

            const float inv = 1.0f / m0;         // 1/m0
            const float M1 = fmaf(b10, m0, fmaf(b11, m1, m2));
            const float M2 = fmaf(b20, m0, fmaf(b21, m1, fmaf(b22, m2,
                             fmaf(b23, m3, m4))));
            const float M3 = fmaf(b30, m0, fmaf(b31, m1, fmaf(b32, m2,
                             fmaf(b33, m3, fmaf(b34, m4, fmaf(b35, m5, m6))))));

            const float n1 = M1 * inv;
            const float n2 = A2 * M2 * inv;
            const float n3 = C6 * M3 * inv;

            union { __half2 h; float f; } pk;
            pk.h = __floats2half2_rn(n2, n3);
            float2 e; e.x = n1; e.y = pk.f;
            nplane[((size_t)i * NLOW + k) * QUP + lane] = e;   // coalesced b64
        }
    }
}

// ---------------------------------------------------------------------------
// K2: product over k + exponent_B + softmax. No LDS, no barriers.
// grid = 2048: bid = jq*256 + i (jq in [0,8)) -> all blocks of an i share
// XCD i%8. block = 256 (4 waves); wave owns 2 j: j = jq*8 + wv*2 + {0,1}.
// ---------------------------------------------------------------------------
__global__ __launch_bounds__(256, 8)
void drn_main(const float2* __restrict__ nplane,
              const float* __restrict__ weight,
              const float* __restrict__ bias_abs,
              const float* __restrict__ bias_q,
              const float* __restrict__ lambda_abs,
              const float* __restrict__ lambda_q,
              float* __restrict__ out)
{
    const int i    = blockIdx.x & 255;
    const int jq   = blockIdx.x >> 8;                            // 0..7
    const int tid  = threadIdx.x;
    const int lane = tid & 63;
    const int wv   = __builtin_amdgcn_readfirstlane(tid >> 6);   // 0..3, uniform
    const int j0   = jq * 8 + wv * 2;

    const float* __restrict__ w0r = weight + (size_t)(j0 + 0) * NLOW;
    const float* __restrict__ w1r = weight + (size_t)(j0 + 1) * NLOW;
    const float2* __restrict__ nb = nplane + (size_t)i * (NLOW * QUP) + lane;

    float pr0 = 1.f, pr1 = 1.f;
    for (int k8 = 0; k8 < 8; ++k8) {
        float2 v[8];
#pragma unroll
        for (int kk = 0; kk < 8; ++kk)
            v[kk] = nb[(size_t)(k8 * 8 + kk) * QUP];             // coalesced b64, L2-hot
        float w0[8], w1[8];
#pragma unroll
        for (int kk = 0; kk < 8; ++kk) {
            w0[kk] = w0r[k8 * 8 + kk];                           // wave-uniform -> s_load
            w1[kk] = w1r[k8 * 8 + kk];
        }
#pragma unroll
        for (int kk = 0; kk < 8; ++kk) {
            union { float f; __half2 h; } pk; pk.f = v[kk].y;
            const float2 n23 = __half22float2(pk.h);             // (n2, n3)
#define STEPJ(W, PR) { const float w_ = (W); \
            float t = fmaf(-w_, n23.y, n23.x); \
            t = fmaf(-w_, t, v[kk].x); \
            PR *= fmaf(-w_, t, 1.0f); }
            STEPJ(w0[kk], pr0)
            STEPJ(w1[kk], pr1)
#undef STEPJ
        }
    }

    // ---- epilogue: exponent_B + base-2 softmax (no max-shift) ----
    const float s1l   = (float)lane * 0.015625f;
    const float LOG2E = 1.4426950408889634f;
    auto finish = [&](float prv, int jj) {
        const int j = j0 + jj;
        const float dq = s1l - lambda_q[j];
        float y = __log2f(prv);                     // |y| <= ~9.3
        y = fmaf(-bias_q[j] * LOG2E, dq * dq, y);
        y = fmaf(-bias_abs[j] * LOG2E, fabsf(s1l - lambda_abs[j]), y);
        const float e = exp2f(y);                   // fp32-safe without max-shift
        float s = e;
#pragma unroll
        for (int off = 32; off >= 1; off >>= 1)
            s += __shfl_xor(s, off, 64);
        out[((size_t)i * NUP + j) * QUP + lane] = e / s;
    };
    finish(pr0, 0);
    finish(pr1, 1);
}

extern "C" void kernel_launch(void* const* d_in, const int* in_sizes, int n_in,
                              void* d_out, int out_size, void* d_ws, size_t ws_size,
                              hipStream_t stream) {
    const float* P          = (const float*)d_in[0];
    const float* weight     = (const float*)d_in[1];
    const float* bias_abs   = (const float*)d_in[2];
    const float* bias_q     = (const float*)d_in[3];
    const float* lambda_abs = (const float*)d_in[4];
    const float* lambda_q   = (const float*)d_in[5];
    (void)in_sizes; (void)n_in; (void)out_size; (void)ws_size;

    float2* nplane = (float2*)d_ws;   // 256*64*64*8 B = 8 MB << ws_size

    drn_prep<<<dim3(256), dim3(512), 0, stream>>>(P, nplane);
    drn_main<<<dim3(2048), dim3(256), 0, stream>>>(
        nplane, weight, bias_abs, bias_q, lambda_abs, lambda_q, (float*)d_out);
}

// Round 3
// 75.462 us; speedup vs baseline: 1.1307x; 1.1307x over previous
//
#include <hip/hip_runtime.h>
#include <hip/hip_fp16.h>

// DRN layer — economized-cubic moment factorization, LOG-ACCUMULATE form (R7).
//
//  x = w*d2, |x| <= h = 0.1*(63/64)^2 = 0.0969.
//  exp(-x) ~= 1 - x + a2*x^2 - x^3/6  (a2 = 1/2 + h^2/24; a0 folded out,
//      cancels in softmax). Per-k factor:
//      poly(w) = 1 - w*n1 + w^2*n2 - w^3*n3,
//      n1 = M1/m0, n2 = a2*M2/m0, n3 = M3/(6 m0),  M_n = sum_m d2^n P[i,k,m].
//  R7 change: accumulate log2(poly) directly instead of the product:
//      log2(poly) ~= -w*a1 + w^2*a2t - w^3*a3t      (w^4 term ~5e-7/k dropped)
//      a1  = L2E*n1, a2t = L2E*(n2 - n1^2/2), a3t = L2E*(n3 - n1*n2 + n1^3/3)
//  -> per (j,k,l): 3 FMA Horner with SGPR w (no power precompute), and the
//     per-j __log2f in the epilogue disappears. |y| <= ~9.3 -> exp2 softmax
//     safe with NO max-shift (unchanged).
//
// Structure = R4 apex (best measured 75.4us): grid 512 (i=bid>>1, jh=bid&1),
// block 512 = 8 waves, 2 blocks/CU, wave owns 4 j. Phase1->2 fused via shfl
// moment broadcast (one barrier total). R5 (2x occupancy) and R6 (kernel
// split) both regressed -> occupancy & barriers falsified; this round tests
// the instruction-count lever: main loop 19 -> 15 instr per (k,lane).

#define NUP 64
#define NLOW 64
#define QUP 64
#define QLOW 64

__global__ __launch_bounds__(512, 4)
void drn_kernel(const float* __restrict__ P,
                const float* __restrict__ weight,
                const float* __restrict__ bias_abs,
                const float* __restrict__ bias_q,
                const float* __restrict__ lambda_abs,
                const float* __restrict__ lambda_q,
                float* __restrict__ out)
{
    __shared__ float2 lds_n[NLOW * QUP];   // (a1 fp32 | a2t,a3t fp16x2)  32 KB

    const int i    = blockIdx.x >> 1;
    const int jh   = blockIdx.x & 1;
    const int tid  = threadIdx.x;
    const int lane = tid & 63;
    const int wv   = __builtin_amdgcn_readfirstlane(tid >> 6);   // 0..7, uniform

    // ---------------- phase 1: raw moments mom_0..6 (wave-local k range) -------
    // lane = (kk, mc): k = wv*8+kk ; m in [mc*8, mc*8+8)
    float t0 = 0.f, t1 = 0.f, t2 = 0.f, t3 = 0.f, t4 = 0.f, t5 = 0.f, t6 = 0.f;
    {
        const int kk = lane >> 3;
        const int mc = lane & 7;
        const int k  = wv * 8 + kk;
        const float* Pr = P + ((size_t)i * NLOW + k) * QLOW + mc * 8;
        const float4 pa = *reinterpret_cast<const float4*>(Pr);
        const float4 pb = *reinterpret_cast<const float4*>(Pr + 4);

        const float s0 = (float)(mc * 8) * 0.015625f;
#define ACCM(PV, S) { float f = (PV); const float s_ = (S); \
        t0 += f; f *= s_; t1 += f; f *= s_; t2 += f; f *= s_; t3 += f; \
        f *= s_; t4 += f; f *= s_; t5 += f; f *= s_; t6 += f; }
        ACCM(pa.x, s0);
        ACCM(pa.y, s0 + 0.015625f);
        ACCM(pa.z, s0 + 0.03125f);
        ACCM(pa.w, s0 + 0.046875f);
        ACCM(pb.x, s0 + 0.0625f);
        ACCM(pb.y, s0 + 0.078125f);
        ACCM(pb.z, s0 + 0.09375f);
        ACCM(pb.w, s0 + 0.109375f);
#undef ACCM
#define RED7(OFF) { t0 += __shfl_xor(t0, OFF, 64); t1 += __shfl_xor(t1, OFF, 64); \
        t2 += __shfl_xor(t2, OFF, 64); t3 += __shfl_xor(t3, OFF, 64); \
        t4 += __shfl_xor(t4, OFF, 64); t5 += __shfl_xor(t5, OFF, 64); \
        t6 += __shfl_xor(t6, OFF, 64); }
        RED7(1) RED7(2) RED7(4)
#undef RED7
        // every lane of 8-lane group kk now holds the full moments of k=wv*8+kk
    }

    // ---------------- phase 2 (fused, no barrier): log-coeff plane -> LDS ------
    const float s1l = (float)lane * 0.015625f;
    {
        const float A2 = 0.50039123f;            // 1/2 + h^2/24
        const float C6 = 1.0f / 6.0f;
        const float L2E = 1.4426950408889634f;
        const float z  = -s1l;
        const float z2 = z * z, z3 = z2 * z, z4 = z2 * z2, z5 = z4 * z, z6 = z4 * z2;
        const float b10 = z2,        b11 = 2.f * z;
        const float b20 = z4,        b21 = 4.f * z3, b22 = 6.f * z2, b23 = 4.f * z;
        const float b30 = z6,        b31 = 6.f * z5, b32 = 15.f * z4,
                    b33 = 20.f * z3, b34 = 15.f * z2, b35 = 6.f * z;

#pragma unroll
        for (int kk = 0; kk < 8; ++kk) {
            const int k = wv * 8 + kk;
            // wave-local broadcast (compile-time src lane -> v_readlane)
            const float m0 = __shfl(t0, kk * 8, 64);
            const float m1 = __shfl(t1, kk * 8, 64);
            const float m2 = __shfl(t2, kk * 8, 64);
            const float m3 = __shfl(t3, kk * 8, 64);
            const float m4 = __shfl(t4, kk * 8, 64);
            const float m5 = __shfl(t5, kk * 8, 64);
            const float m6 = __shfl(t6, kk * 8, 64);

            const float inv = 1.0f / m0;
            const float M1 = fmaf(b10, m0, fmaf(b11, m1, m2));
            const float M2 = fmaf(b20, m0, fmaf(b21, m1, fmaf(b22, m2,
                             fmaf(b23, m3, m4))));
            const float M3 = fmaf(b30, m0, fmaf(b31, m1, fmaf(b32, m2,
                             fmaf(b33, m3, fmaf(b34, m4, fmaf(b35, m5, m6))))));

            const float n1 = M1 * inv;
            const float n2 = A2 * M2 * inv;
            const float n3 = C6 * M3 * inv;

            // log-expansion coefficients (L2E folded in):
            //   log2(poly) = -w*a1 + w^2*a2t - w^3*a3t + O(w^4)
            const float a1  = L2E * n1;
            const float a2t = L2E * fmaf(-0.5f * n1, n1, n2);
            const float n1n2 = n1 * n2;
            const float a3t = L2E * fmaf(0.33333334f * n1, n1 * n1, n3 - n1n2);

            union { __half2 h; float f; } pk;
            pk.h = __floats2half2_rn(a2t, a3t);
            float2 e; e.x = a1; e.y = pk.f;
            lds_n[k * QUP + lane] = e;
        }
    }
    __syncthreads();   // cross-wave: main loop reads all 64 k

    // ---------------- main loop: 64 k fully unrolled, this wave's 4 j's --------
    // Weight rows are wave-uniform -> s_load (compiler merges to dwordx8).
    const float* __restrict__ w0r = weight + (size_t)(jh * 32 + wv * 4 + 0) * NLOW;
    const float* __restrict__ w1r = weight + (size_t)(jh * 32 + wv * 4 + 1) * NLOW;
    const float* __restrict__ w2r = weight + (size_t)(jh * 32 + wv * 4 + 2) * NLOW;
    const float* __restrict__ w3r = weight + (size_t)(jh * 32 + wv * 4 + 3) * NLOW;

    float y0 = 0.f, y1 = 0.f, y2 = 0.f, y3 = 0.f;
#pragma unroll
    for (int k8 = 0; k8 < 8; ++k8) {
        float w0[8], w1[8], w2[8], w3[8];
#pragma unroll
        for (int kk = 0; kk < 8; ++kk) {
            w0[kk] = w0r[k8 * 8 + kk];
            w1[kk] = w1r[k8 * 8 + kk];
            w2[kk] = w2r[k8 * 8 + kk];
            w3[kk] = w3r[k8 * 8 + kk];
        }
#pragma unroll
        for (int kk = 0; kk < 8; ++kk) {
            const float2 v = lds_n[(k8 * 8 + kk) * QUP + lane];  // imm-offset b64
            union { float f; __half2 h; } pk; pk.f = v.y;
            const float2 a23 = __half22float2(pk.h);             // (a2t, a3t)
#define STEPJ(W, Y) { const float w_ = (W); \
            float t = fmaf(-w_, a23.y, a23.x); \
            t = fmaf(-w_, t, v.x); \
            Y = fmaf(-w_, t, Y); }
            STEPJ(w0[kk], y0)
            STEPJ(w1[kk], y1)
            STEPJ(w2[kk], y2)
            STEPJ(w3[kk], y3)
#undef STEPJ
        }
    }

    // ---------------- epilogue: exponent_B + base-2 softmax (no max-shift) -----
    const float LOG2E = 1.4426950408889634f;
    auto finish = [&](float yv, int jj) {
        const int j = jh * 32 + wv * 4 + jj;
        const float dq = s1l - lambda_q[j];
        float y = yv;                               // already log2-accumulated
        y = fmaf(-bias_q[j] * LOG2E, dq * dq, y);
        y = fmaf(-bias_abs[j] * LOG2E, fabsf(s1l - lambda_abs[j]), y);
        const float e = exp2f(y);                   // fp32-safe without max-shift
        float s = e;
#pragma unroll
        for (int off = 32; off >= 1; off >>= 1)
            s += __shfl_xor(s, off, 64);
        out[((size_t)i * NUP + j) * QUP + lane] = e * __builtin_amdgcn_rcpf(s);
    };
    finish(y0, 0);
    finish(y1, 1);
    finish(y2, 2);
    finish(y3, 3);
}

extern "C" void kernel_launch(void* const* d_in, const int* in_sizes, int n_in,
                              void* d_out, int out_size, void* d_ws, size_t ws_size,
                              hipStream_t stream) {
    const float* P          = (const float*)d_in[0];
    const float* weight     = (const float*)d_in[1];
    const float* bias_abs   = (const float*)d_in[2];
    const float* bias_q     = (const float*)d_in[3];
    const float* lambda_abs = (const float*)d_in[4];
    const float* lambda_q   = (const float*)d_in[5];
    (void)in_sizes; (void)n_in; (void)out_size; (void)d_ws; (void)ws_size;

    drn_kernel<<<dim3(512), dim3(512), 0, stream>>>(
        P, weight, bias_abs, bias_q, lambda_abs, lambda_q, (float*)d_out);
}